// Round 4
// baseline (96669.220 us; speedup 1.0000x reference)
//
#include <hip/hip_runtime.h>

typedef unsigned short u16;
typedef unsigned int u32;
typedef __attribute__((ext_vector_type(8))) short bf16x8;
typedef __attribute__((ext_vector_type(4))) float f32x4;

#define S_LEN 5120
#define UB 64
#define GA 1152

__device__ __forceinline__ float bf2f(u16 u) { return __uint_as_float(((u32)u) << 16); }
__device__ __forceinline__ u16 f2bf(float f) {
    u32 x = __float_as_uint(f);
    return (u16)((x + 0x7fffu + ((x >> 16) & 1u)) >> 16);
}
__device__ __forceinline__ float blo(u32 w) { return __uint_as_float(w << 16); }
__device__ __forceinline__ float bhi(u32 w) { return __uint_as_float(w & 0xffff0000u); }
__device__ __forceinline__ float sigm(float x) { return 1.f / (1.f + __expf(-x)); }
__device__ __forceinline__ float tanh_(float x) { float e = __expf(2.f * x); return 1.f - 2.f / (e + 1.f); }

#if __has_builtin(__builtin_amdgcn_fdot2)
typedef _Float16 h2v __attribute__((ext_vector_type(2)));
__device__ __forceinline__ float dot2p(u32 w, u32 h, float acc) {
    return __builtin_amdgcn_fdot2(__builtin_bit_cast(h2v, w), __builtin_bit_cast(h2v, h), acc, false);
}
__device__ __forceinline__ u32 packpair(float a, float b) {
    u16 x = __builtin_bit_cast(u16, (_Float16)a);
    u16 y = __builtin_bit_cast(u16, (_Float16)b);
    return (u32)x | ((u32)y << 16);
}
__device__ __forceinline__ u16 pack1(float a) { return __builtin_bit_cast(u16, (_Float16)a); }
#else
__device__ __forceinline__ float dot2p(u32 w, u32 h, float acc) {
    acc = fmaf(blo(w), blo(h), acc);
    return fmaf(bhi(w), bhi(h), acc);
}
__device__ __forceinline__ u32 packpair(float a, float b) { return (u32)f2bf(a) | ((u32)f2bf(b) << 16); }
__device__ __forceinline__ u16 pack1(float a) { return f2bf(a); }
#endif

__device__ __forceinline__ float sum8(const float* p) {
    float4 a = *(const float4*)p;
    float4 c = *(const float4*)(p + 4);
    return ((a.x + a.y) + (a.z + a.w)) + ((c.x + c.y) + (c.z + c.w));
}

// ---------------- convert grua_wih to bf16 ----------------
__global__ __launch_bounds__(256) void k_cvt(const float* __restrict__ src, u16* __restrict__ dst) {
    int i = blockIdx.x * 256 + threadIdx.x;
    dst[i] = f2bf(src[i]);
}

// ---------------- frame-rate network ----------------
__global__ __launch_bounds__(128) void k_frame1(const float* __restrict__ features, const int* __restrict__ periods,
                                                const float* __restrict__ pemb, const float* __restrict__ w,
                                                const float* __restrict__ bias, float* __restrict__ c1) {
    __shared__ float fin[3][84];
    int t = blockIdx.x, b = blockIdx.y, o = threadIdx.x;
    for (int i = threadIdx.x; i < 252; i += 128) {
        int kk = i / 84, ci = i % 84, tt = t + kk;
        float v;
        if (ci < 20) v = features[(b * 36 + tt) * 20 + ci];
        else v = pemb[periods[b * 36 + tt] * 64 + (ci - 20)];
        fin[kk][ci] = v;
    }
    __syncthreads();
    float acc = bias[o];
    for (int kk = 0; kk < 3; kk++)
        for (int ci = 0; ci < 84; ci++)
            acc = fmaf(fin[kk][ci], w[o * 252 + ci * 3 + kk], acc);
    c1[(b * 34 + t) * 128 + o] = tanh_(acc);
}

__global__ __launch_bounds__(128) void k_frame2(const float* __restrict__ c1, const float* __restrict__ w,
                                                const float* __restrict__ bias, float* __restrict__ c2) {
    __shared__ float fin[3][128];
    int t = blockIdx.x, b = blockIdx.y, o = threadIdx.x;
    for (int i = threadIdx.x; i < 384; i += 128) {
        int kk = i >> 7, ci = i & 127;
        fin[kk][ci] = c1[(b * 34 + t + kk) * 128 + ci];
    }
    __syncthreads();
    float acc = bias[o];
    for (int kk = 0; kk < 3; kk++)
        for (int ci = 0; ci < 128; ci++)
            acc = fmaf(fin[kk][ci], w[o * 384 + ci * 3 + kk], acc);
    c2[(b * 32 + t) * 128 + o] = tanh_(acc);
}

__global__ __launch_bounds__(128) void k_fd(const float* __restrict__ c2, const float* __restrict__ w1,
                                            const float* __restrict__ b1, const float* __restrict__ w2,
                                            const float* __restrict__ b2, float* __restrict__ cc) {
    __shared__ float a0[128], a1s[128];
    int t = blockIdx.x, b = blockIdx.y, o = threadIdx.x;
    a0[o] = c2[(b * 32 + t) * 128 + o];
    __syncthreads();
    float acc = b1[o];
    for (int k = 0; k < 128; k++) acc = fmaf(a0[k], w1[o * 128 + k], acc);
    a1s[o] = tanh_(acc);
    __syncthreads();
    float acc2 = b2[o];
    for (int k = 0; k < 128; k++) acc2 = fmaf(a1s[k], w2[o * 128 + k], acc2);
    cc[(b * 32 + t) * 128 + o] = tanh_(acc2);
}

// cpart[b][fr][192] = grub_wih[:,384:512] @ c[b][fr] + grub_bih
__global__ __launch_bounds__(192) void k_cpart(const float* __restrict__ cc, const float* __restrict__ wihB,
                                               const float* __restrict__ bihB, float* __restrict__ cpart) {
    __shared__ float cl[128];
    int fr = blockIdx.x, b = blockIdx.y, o = threadIdx.x;
    if (o < 128) cl[o] = cc[(b * 32 + fr) * 128 + o];
    __syncthreads();
    float acc = bihB[o];
    for (int k = 0; k < 128; k++) acc = fmaf(cl[k], wihB[o * 512 + 384 + k], acc);
    cpart[((size_t)b * 32 + fr) * 192 + o] = acc;
}

// ---------------- GRU-A input projection GEMM ----------------
__global__ __launch_bounds__(256) void k_gemm(const int* __restrict__ signals, const float* __restrict__ semb,
                                              const float* __restrict__ c, const u16* __restrict__ wih,
                                              const float* __restrict__ bih, u16* __restrict__ xp) {
    __shared__ u16 As[64][40];
    __shared__ u16 Bs[64][40];
    int m0 = blockIdx.x * 64, n0 = blockIdx.y * 64;
    int tid = threadIdx.x;
    int r = tid >> 2, kc = tid & 3;
    int lane = tid & 63, wv = tid >> 6;
    int wr = wv >> 1, wc = wv & 1;
    int mrow = m0 + r;
    int b = mrow / S_LEN, s = mrow % S_LEN;
    const int* sigrow = signals + mrow * 3;
    const float* crow = c + ((size_t)(b * 32) + s / 160) * 128;
    f32x4 acc[2][2];
#pragma unroll
    for (int i = 0; i < 2; i++)
#pragma unroll
        for (int j = 0; j < 2; j++) { acc[i][j][0] = 0.f; acc[i][j][1] = 0.f; acc[i][j][2] = 0.f; acc[i][j][3] = 0.f; }
    for (int k0 = 0; k0 < 512; k0 += 32) {
        int k = k0 + kc * 8;
        float v[8];
        if (k < 384) {
            int idx = sigrow[k >> 7];
            const float* src = semb + idx * 128 + (k & 127);
#pragma unroll
            for (int j = 0; j < 8; j++) v[j] = src[j];
        } else {
            const float* src = crow + (k - 384);
#pragma unroll
            for (int j = 0; j < 8; j++) v[j] = src[j];
        }
        u32 pk[4];
#pragma unroll
        for (int j = 0; j < 4; j++) pk[j] = (u32)f2bf(v[2 * j]) | ((u32)f2bf(v[2 * j + 1]) << 16);
        *(uint4*)&As[r][kc * 8] = *(uint4*)pk;
        *(uint4*)&Bs[r][kc * 8] = *(const uint4*)&wih[(size_t)(n0 + r) * 512 + k];
        __syncthreads();
        bf16x8 af[2], bfr[2];
#pragma unroll
        for (int mi = 0; mi < 2; mi++) af[mi] = *(const bf16x8*)&As[wr * 32 + mi * 16 + (lane & 15)][(lane >> 4) * 8];
#pragma unroll
        for (int ni = 0; ni < 2; ni++) bfr[ni] = *(const bf16x8*)&Bs[wc * 32 + ni * 16 + (lane & 15)][(lane >> 4) * 8];
#pragma unroll
        for (int mi = 0; mi < 2; mi++)
#pragma unroll
            for (int ni = 0; ni < 2; ni++)
                acc[mi][ni] = __builtin_amdgcn_mfma_f32_16x16x32_bf16(af[mi], bfr[ni], acc[mi][ni], 0, 0, 0);
        __syncthreads();
    }
#pragma unroll
    for (int mi = 0; mi < 2; mi++)
#pragma unroll
        for (int ni = 0; ni < 2; ni++) {
            int row = m0 + wr * 32 + mi * 16 + (lane >> 4) * 4;
            int col = n0 + wc * 32 + ni * 16 + (lane & 15);
            float bias = bih[col];
#pragma unroll
            for (int i = 0; i < 4; i++)
                xp[(size_t)(row + i) * GA + col] = f2bf(acc[mi][ni][i] + bias);
        }
}

// ---------------- the serial GRU kernel: ONE WG per batch, weights in VGPRs ----------------
// thread (g=tid>>3, q=tid&7): A rows 9g..9g+9 over K-slice [48q,48q+48)
// tid>=512: GRU-B input matvec rows rr,rr+64,rr+128 (rr=(tid-512)>>3), same K-slice of hA
// tid<384:  GRU-B hidden matvec row tid>>1, half qb=tid&1 of hB
// gates: tid<384 -> A unit tid; tid in [384,448) -> B unit tid-384
struct __align__(16) SMem1 {
    uint4 hbuf4[2][52];   // hA packed 16-bit: 384 elems = 48 uint4 (+pad)
    uint4 hbb4[2][8];     // hB packed 16-bit: 64 elems = 8 uint4
    float redA[1152][8];  // A partials [row][q]
    float redBy[192][8];  // B-y partials
    float redBh[192][2];  // B-h partials
    float cpl[32][196];   // cpart per frame
};

__global__ __launch_bounds__(1024, 4) void k_serial(
        const float* __restrict__ whhA, const float* __restrict__ bhhA,
        const float* __restrict__ wihB, const float* __restrict__ whhB,
        const float* __restrict__ bhhB, const u16* __restrict__ xp,
        const float* __restrict__ cpart, const float* __restrict__ h0a,
        const float* __restrict__ h0b, float* __restrict__ yB) {
    __shared__ SMem1 s;
    const int b = blockIdx.x;
    const int tid = threadIdx.x;
    const int g = tid >> 3, q = tid & 7;

    // ---- load weights into registers (packed 16-bit pairs) ----
    u32 wA[9][24];
#pragma unroll
    for (int r = 0; r < 9; r++) {
        const float* wrow = whhA + (size_t)(9 * g + r) * 384 + 48 * q;
#pragma unroll
        for (int i = 0; i < 12; i++) {
            float4 v = *(const float4*)(wrow + 4 * i);
            wA[r][2 * i] = packpair(v.x, v.y);
            wA[r][2 * i + 1] = packpair(v.z, v.w);
        }
    }
    u32 wBy[3][24];
    const int rr = (tid - 512) >> 3;
    if (tid >= 512) {
#pragma unroll
        for (int j3 = 0; j3 < 3; j3++) {
            const float* wrow = wihB + (size_t)(rr + 64 * j3) * 512 + 48 * q;
#pragma unroll
            for (int i = 0; i < 12; i++) {
                float4 v = *(const float4*)(wrow + 4 * i);
                wBy[j3][2 * i] = packpair(v.x, v.y);
                wBy[j3][2 * i + 1] = packpair(v.z, v.w);
            }
        }
    }
    u32 wbh[16];
    const int r3 = tid >> 1, qb = tid & 1;
    if (tid < 384) {
        const float* wrow = whhB + (size_t)r3 * 64 + 32 * qb;
#pragma unroll
        for (int i = 0; i < 8; i++) {
            float4 v = *(const float4*)(wrow + 4 * i);
            wbh[2 * i] = packpair(v.x, v.y);
            wbh[2 * i + 1] = packpair(v.z, v.w);
        }
    }

    // ---- LDS: cpart ----
    for (int i = tid; i < 32 * 192; i += 1024)
        s.cpl[i / 192][i % 192] = cpart[((size_t)b * 32) * 192 + i];

    // ---- biases + persistent h in gate-thread registers ----
    float bA0 = 0, bA1 = 0, bA2 = 0, bB0 = 0, bB1 = 0, bB2 = 0, hprA = 0, hprB = 0;
    if (tid < 384) {
        bA0 = bhhA[tid]; bA1 = bhhA[384 + tid]; bA2 = bhhA[768 + tid];
        hprA = h0a[b * 384 + tid];
    } else if (tid < 448) {
        int u = tid - 384;
        bB0 = bhhB[u]; bB1 = bhhB[64 + u]; bB2 = bhhB[128 + u];
        hprB = h0b[b * 64 + u];
    }
    // ---- initial h into LDS (packed) ----
    if (tid < 192) {
        ((u32*)s.hbuf4[0])[tid] = packpair(h0a[b * 384 + 2 * tid], h0a[b * 384 + 2 * tid + 1]);
    } else if (tid < 224) {
        int k = tid - 192;
        ((u32*)s.hbb4[0])[k] = packpair(h0b[b * 64 + 2 * k], h0b[b * 64 + 2 * k + 1]);
    }
    __syncthreads();

    for (int t = 0; t <= S_LEN; ++t) {
        const int p = t & 1;
        const bool hasA = (t < S_LEN), hasB = (t > 0);
        // xp(t) loads for this step's A-gates (consumed after the barrier)
        u16 xq0 = 0, xq1 = 0, xq2 = 0;
        if (hasA && tid < 384) {
            const u16* xrow = xp + (size_t)(b * S_LEN + t) * GA;
            xq0 = xrow[tid]; xq1 = xrow[384 + tid]; xq2 = xrow[768 + tid];
        }
        // hA(t-1) slice from LDS
        uint4 hh[6];
#pragma unroll
        for (int i = 0; i < 6; i++) hh[i] = s.hbuf4[p][q * 6 + i];
        // ---- A matvec ----
        if (hasA) {
#pragma unroll
            for (int r = 0; r < 9; r++) {
                float a0 = 0, a1 = 0;
#pragma unroll
                for (int j = 0; j < 3; j++) {
                    uint4 h0 = hh[2 * j], h1 = hh[2 * j + 1];
                    a0 = dot2p(wA[r][8 * j + 0], h0.x, a0);
                    a1 = dot2p(wA[r][8 * j + 1], h0.y, a1);
                    a0 = dot2p(wA[r][8 * j + 2], h0.z, a0);
                    a1 = dot2p(wA[r][8 * j + 3], h0.w, a1);
                    a0 = dot2p(wA[r][8 * j + 4], h1.x, a0);
                    a1 = dot2p(wA[r][8 * j + 5], h1.y, a1);
                    a0 = dot2p(wA[r][8 * j + 6], h1.z, a0);
                    a1 = dot2p(wA[r][8 * j + 7], h1.w, a1);
                }
                s.redA[9 * g + r][q] = a0 + a1;
            }
        }
        // ---- B matvecs (computing hB(t-1)) ----
        if (hasB) {
            if (tid >= 512) {
#pragma unroll
                for (int j3 = 0; j3 < 3; j3++) {
                    float a0 = 0, a1 = 0;
#pragma unroll
                    for (int j = 0; j < 3; j++) {
                        uint4 h0 = hh[2 * j], h1 = hh[2 * j + 1];
                        a0 = dot2p(wBy[j3][8 * j + 0], h0.x, a0);
                        a1 = dot2p(wBy[j3][8 * j + 1], h0.y, a1);
                        a0 = dot2p(wBy[j3][8 * j + 2], h0.z, a0);
                        a1 = dot2p(wBy[j3][8 * j + 3], h0.w, a1);
                        a0 = dot2p(wBy[j3][8 * j + 4], h1.x, a0);
                        a1 = dot2p(wBy[j3][8 * j + 5], h1.y, a1);
                        a0 = dot2p(wBy[j3][8 * j + 6], h1.z, a0);
                        a1 = dot2p(wBy[j3][8 * j + 7], h1.w, a1);
                    }
                    s.redBy[rr + 64 * j3][q] = a0 + a1;
                }
            } else if (tid < 384) {
                uint4 hb[4];
#pragma unroll
                for (int i = 0; i < 4; i++) hb[i] = s.hbb4[p ^ 1][qb * 4 + i];
                float a0 = 0, a1 = 0;
#pragma unroll
                for (int i = 0; i < 4; i++) {
                    a0 = dot2p(wbh[4 * i + 0], hb[i].x, a0);
                    a1 = dot2p(wbh[4 * i + 1], hb[i].y, a1);
                    a0 = dot2p(wbh[4 * i + 2], hb[i].z, a0);
                    a1 = dot2p(wbh[4 * i + 3], hb[i].w, a1);
                }
                s.redBh[r3][qb] = a0 + a1;
            }
        }
        __syncthreads();
        // ---- gates ----
        if (hasA && tid < 384) {
            const int u = tid;
            float pr = sum8(s.redA[u]) + bA0;
            float pz = sum8(s.redA[384 + u]) + bA1;
            float pn = sum8(s.redA[768 + u]) + bA2;
            float rg = sigm(bf2f(xq0) + pr);
            float zg = sigm(bf2f(xq1) + pz);
            float ng = tanh_(bf2f(xq2) + rg * pn);
            float hnew = (1.f - zg) * ng + zg * hprA;
            hprA = hnew;
            ((u16*)s.hbuf4[p ^ 1])[u] = pack1(hnew);
        }
        if (hasB && tid >= 384 && tid < 448) {
            const int u = tid - 384;
            const int fr = (t - 1) / 160;
            float xr = sum8(s.redBy[u]) + s.cpl[fr][u];
            float xz = sum8(s.redBy[64 + u]) + s.cpl[fr][64 + u];
            float xn = sum8(s.redBy[128 + u]) + s.cpl[fr][128 + u];
            float hr = s.redBh[u][0] + s.redBh[u][1] + bB0;
            float hz = s.redBh[64 + u][0] + s.redBh[64 + u][1] + bB1;
            float hn = s.redBh[128 + u][0] + s.redBh[128 + u][1] + bB2;
            float rg = sigm(xr + hr);
            float zg = sigm(xz + hz);
            float ng = tanh_(xn + rg * hn);
            float hbnew = (1.f - zg) * ng + zg * hprB;
            hprB = hbnew;
            ((u16*)s.hbb4[p])[u] = pack1(hbnew);
            yB[((size_t)b * S_LEN + (t - 1)) * UB + u] = hbnew;
        }
        __syncthreads();
    }
}

// ---------------- dual FC + log_softmax ----------------
__global__ __launch_bounds__(256) void k_fc(const float* __restrict__ yB, const float* __restrict__ w1,
                                            const float* __restrict__ b1, const float* __restrict__ w2,
                                            const float* __restrict__ b2, const float* __restrict__ alpha,
                                            const float* __restrict__ beta, float* __restrict__ out) {
    __shared__ float yb[4][64];
    __shared__ float vb[4][256];
    int tid = threadIdx.x;
    size_t r0 = (size_t)blockIdx.x * 4;
    { int r = tid >> 6, k = tid & 63; yb[r][k] = yB[(r0 + r) * 64 + k]; }
    __syncthreads();
    int o = tid;
    float a1[4] = {0, 0, 0, 0}, a2[4] = {0, 0, 0, 0};
    for (int k = 0; k < 64; k += 4) {
        float4 u = *(const float4*)(w1 + o * 64 + k);
        float4 v = *(const float4*)(w2 + o * 64 + k);
#pragma unroll
        for (int r = 0; r < 4; r++) {
            float y0 = yb[r][k], y1 = yb[r][k + 1], y2 = yb[r][k + 2], y3 = yb[r][k + 3];
            a1[r] = fmaf(u.x, y0, fmaf(u.y, y1, fmaf(u.z, y2, fmaf(u.w, y3, a1[r]))));
            a2[r] = fmaf(v.x, y0, fmaf(v.y, y1, fmaf(v.z, y2, fmaf(v.w, y3, a2[r]))));
        }
    }
    float al = alpha[o], be = beta[o], c1 = b1[o], c2 = b2[o];
#pragma unroll
    for (int r = 0; r < 4; r++)
        vb[r][o] = al * tanh_(a1[r] + c1) + be * tanh_(a2[r] + c2);
    __syncthreads();
    int wv = tid >> 6, l = tid & 63;
    float x0 = vb[wv][l], x1 = vb[wv][64 + l], x2 = vb[wv][128 + l], x3 = vb[wv][192 + l];
    float m = fmaxf(fmaxf(x0, x1), fmaxf(x2, x3));
#pragma unroll
    for (int off = 1; off < 64; off <<= 1) m = fmaxf(m, __shfl_xor(m, off));
    float sum = __expf(x0 - m) + __expf(x1 - m) + __expf(x2 - m) + __expf(x3 - m);
#pragma unroll
    for (int off = 1; off < 64; off <<= 1) sum += __shfl_xor(sum, off);
    float lse = m + __logf(sum);
    float* po = out + (r0 + wv) * 256;
    po[l] = x0 - lse;
    po[64 + l] = x1 - lse;
    po[128 + l] = x2 - lse;
    po[192 + l] = x3 - lse;
}

extern "C" void kernel_launch(void* const* d_in, const int* in_sizes, int n_in,
                              void* d_out, int out_size, void* d_ws, size_t ws_size,
                              hipStream_t stream) {
    const float* features = (const float*)d_in[0];
    const int* periods = (const int*)d_in[1];
    const int* signals = (const int*)d_in[2];
    const float* gruA0 = (const float*)d_in[3];
    const float* gruB0 = (const float*)d_in[4];
    const float* period_emb = (const float*)d_in[5];
    const float* signal_emb = (const float*)d_in[6];
    const float* conv1_w = (const float*)d_in[7];
    const float* conv1_b = (const float*)d_in[8];
    const float* conv2_w = (const float*)d_in[9];
    const float* conv2_b = (const float*)d_in[10];
    const float* fd1_w = (const float*)d_in[11];
    const float* fd1_b = (const float*)d_in[12];
    const float* fd2_w = (const float*)d_in[13];
    const float* fd2_b = (const float*)d_in[14];
    const float* grua_wih = (const float*)d_in[15];
    const float* grua_whh = (const float*)d_in[16];
    const float* grua_bih = (const float*)d_in[17];
    const float* grua_bhh = (const float*)d_in[18];
    const float* grub_wih = (const float*)d_in[19];
    const float* grub_whh = (const float*)d_in[20];
    const float* grub_bih = (const float*)d_in[21];
    const float* grub_bhh = (const float*)d_in[22];
    const float* fc1_w = (const float*)d_in[23];
    const float* fc1_b = (const float*)d_in[24];
    const float* fc2_w = (const float*)d_in[25];
    const float* fc2_b = (const float*)d_in[26];
    const float* alpha = (const float*)d_in[27];
    const float* beta = (const float*)d_in[28];
    float* out = (float*)d_out;

    char* ws = (char*)d_ws;
    size_t off = 0;
    auto alloc = [&](size_t bytes) { void* p = ws + off; off += (bytes + 255) & ~(size_t)255; return p; };
    u16* xp = (u16*)alloc((size_t)16 * 5120 * 1152 * 2);
    u16* wihA = (u16*)alloc((size_t)1152 * 512 * 2);
    float* c1 = (float*)alloc((size_t)16 * 34 * 128 * 4);
    float* c2 = (float*)alloc((size_t)16 * 32 * 128 * 4);
    float* cc = (float*)alloc((size_t)16 * 32 * 128 * 4);
    float* cpart = (float*)alloc((size_t)16 * 32 * 192 * 4);
    float* yB = (float*)alloc((size_t)16 * 5120 * 64 * 4);

    k_cvt<<<dim3(2304), dim3(256), 0, stream>>>(grua_wih, wihA);
    k_frame1<<<dim3(34, 16), dim3(128), 0, stream>>>(features, periods, period_emb, conv1_w, conv1_b, c1);
    k_frame2<<<dim3(32, 16), dim3(128), 0, stream>>>(c1, conv2_w, conv2_b, c2);
    k_fd<<<dim3(32, 16), dim3(128), 0, stream>>>(c2, fd1_w, fd1_b, fd2_w, fd2_b, cc);
    k_cpart<<<dim3(32, 16), dim3(192), 0, stream>>>(cc, grub_wih, grub_bih, cpart);
    k_gemm<<<dim3(1280, 18), dim3(256), 0, stream>>>(signals, signal_emb, cc, wihA, grua_bih, xp);
    k_serial<<<dim3(16), dim3(1024), 0, stream>>>(grua_whh, grua_bhh, grub_wih, grub_whh, grub_bhh,
                                                  xp, cpart, gruA0, gruB0, yB);
    k_fc<<<dim3(20480), dim3(256), 0, stream>>>(yB, fc1_w, fc1_b, fc2_w, fc2_b, alpha, beta, out);
}

// Round 5
// 43130.801 us; speedup vs baseline: 2.2413x; 2.2413x over previous
//
#include <hip/hip_runtime.h>

typedef unsigned short u16;
typedef unsigned int u32;
typedef unsigned long long u64;
typedef __attribute__((ext_vector_type(8))) short bf16x8;
typedef __attribute__((ext_vector_type(4))) float f32x4;

#define S_LEN 5120
#define UB 64
#define GA 1152
#define CAPP (1 << 18)

__device__ __forceinline__ float bf2f(u16 u) { return __uint_as_float(((u32)u) << 16); }
__device__ __forceinline__ u16 f2bf(float f) {
    u32 x = __float_as_uint(f);
    return (u16)((x + 0x7fffu + ((x >> 16) & 1u)) >> 16);
}
__device__ __forceinline__ float sigm(float x) { return 1.f / (1.f + __expf(-x)); }
__device__ __forceinline__ float tanh_(float x) { float e = __expf(2.f * x); return 1.f - 2.f / (e + 1.f); }

__device__ __forceinline__ u64 ald64(const u64* p) {
    return __hip_atomic_load(p, __ATOMIC_RELAXED, __HIP_MEMORY_SCOPE_AGENT);
}
__device__ __forceinline__ void ast32(u32* p, u32 v) {
    __hip_atomic_store(p, v, __ATOMIC_RELAXED, __HIP_MEMORY_SCOPE_AGENT);
}
__device__ __forceinline__ bf16x8 ld_frag_f32(const float* p) {
    bf16x8 r;
#pragma unroll
    for (int j = 0; j < 8; j++) r[j] = (short)f2bf(p[j]);
    return r;
}

// ---------------- convert grua_wih to bf16 ----------------
__global__ __launch_bounds__(256) void k_cvt(const float* __restrict__ src, u16* __restrict__ dst) {
    int i = blockIdx.x * 256 + threadIdx.x;
    dst[i] = f2bf(src[i]);
}

// ---------------- frame-rate network ----------------
__global__ __launch_bounds__(128) void k_frame1(const float* __restrict__ features, const int* __restrict__ periods,
                                                const float* __restrict__ pemb, const float* __restrict__ w,
                                                const float* __restrict__ bias, float* __restrict__ c1) {
    __shared__ float fin[3][84];
    int t = blockIdx.x, b = blockIdx.y, o = threadIdx.x;
    for (int i = threadIdx.x; i < 252; i += 128) {
        int kk = i / 84, ci = i % 84, tt = t + kk;
        float v;
        if (ci < 20) v = features[(b * 36 + tt) * 20 + ci];
        else v = pemb[periods[b * 36 + tt] * 64 + (ci - 20)];
        fin[kk][ci] = v;
    }
    __syncthreads();
    float acc = bias[o];
    for (int kk = 0; kk < 3; kk++)
        for (int ci = 0; ci < 84; ci++)
            acc = fmaf(fin[kk][ci], w[o * 252 + ci * 3 + kk], acc);
    c1[(b * 34 + t) * 128 + o] = tanh_(acc);
}

__global__ __launch_bounds__(128) void k_frame2(const float* __restrict__ c1, const float* __restrict__ w,
                                                const float* __restrict__ bias, float* __restrict__ c2) {
    __shared__ float fin[3][128];
    int t = blockIdx.x, b = blockIdx.y, o = threadIdx.x;
    for (int i = threadIdx.x; i < 384; i += 128) {
        int kk = i >> 7, ci = i & 127;
        fin[kk][ci] = c1[(b * 34 + t + kk) * 128 + ci];
    }
    __syncthreads();
    float acc = bias[o];
    for (int kk = 0; kk < 3; kk++)
        for (int ci = 0; ci < 128; ci++)
            acc = fmaf(fin[kk][ci], w[o * 384 + ci * 3 + kk], acc);
    c2[(b * 32 + t) * 128 + o] = tanh_(acc);
}

__global__ __launch_bounds__(128) void k_fd(const float* __restrict__ c2, const float* __restrict__ w1,
                                            const float* __restrict__ b1, const float* __restrict__ w2,
                                            const float* __restrict__ b2, float* __restrict__ cc) {
    __shared__ float a0[128], a1s[128];
    int t = blockIdx.x, b = blockIdx.y, o = threadIdx.x;
    a0[o] = c2[(b * 32 + t) * 128 + o];
    __syncthreads();
    float acc = b1[o];
    for (int k = 0; k < 128; k++) acc = fmaf(a0[k], w1[o * 128 + k], acc);
    a1s[o] = tanh_(acc);
    __syncthreads();
    float acc2 = b2[o];
    for (int k = 0; k < 128; k++) acc2 = fmaf(a1s[k], w2[o * 128 + k], acc2);
    cc[(b * 32 + t) * 128 + o] = tanh_(acc2);
}

// cpart[b][fr][192] = grub_wih[:,384:512] @ c[b][fr] + grub_bih
__global__ __launch_bounds__(192) void k_cpart(const float* __restrict__ cc, const float* __restrict__ wihB,
                                               const float* __restrict__ bihB, float* __restrict__ cpart) {
    __shared__ float cl[128];
    int fr = blockIdx.x, b = blockIdx.y, o = threadIdx.x;
    if (o < 128) cl[o] = cc[(b * 32 + fr) * 128 + o];
    __syncthreads();
    float acc = bihB[o];
    for (int k = 0; k < 128; k++) acc = fmaf(cl[k], wihB[o * 512 + 384 + k], acc);
    cpart[((size_t)b * 32 + fr) * 192 + o] = acc;
}

// ---------------- init: clear stale tags ----------------
__global__ __launch_bounds__(256) void k_init(u32* hEx) {
    hEx[blockIdx.x * 256 + threadIdx.x] = 0u;
}

// ---------------- GRU-A input projection GEMM ----------------
__global__ __launch_bounds__(256) void k_gemm(const int* __restrict__ signals, const float* __restrict__ semb,
                                              const float* __restrict__ c, const u16* __restrict__ wih,
                                              const float* __restrict__ bih, u16* __restrict__ xp) {
    __shared__ u16 As[64][40];
    __shared__ u16 Bs[64][40];
    int m0 = blockIdx.x * 64, n0 = blockIdx.y * 64;
    int tid = threadIdx.x;
    int r = tid >> 2, kc = tid & 3;
    int lane = tid & 63, wv = tid >> 6;
    int wr = wv >> 1, wc = wv & 1;
    int mrow = m0 + r;
    int b = mrow / S_LEN, s = mrow % S_LEN;
    const int* sigrow = signals + mrow * 3;
    const float* crow = c + ((size_t)(b * 32) + s / 160) * 128;
    f32x4 acc[2][2];
#pragma unroll
    for (int i = 0; i < 2; i++)
#pragma unroll
        for (int j = 0; j < 2; j++) { acc[i][j][0] = 0.f; acc[i][j][1] = 0.f; acc[i][j][2] = 0.f; acc[i][j][3] = 0.f; }
    for (int k0 = 0; k0 < 512; k0 += 32) {
        int k = k0 + kc * 8;
        float v[8];
        if (k < 384) {
            int idx = sigrow[k >> 7];
            const float* src = semb + idx * 128 + (k & 127);
#pragma unroll
            for (int j = 0; j < 8; j++) v[j] = src[j];
        } else {
            const float* src = crow + (k - 384);
#pragma unroll
            for (int j = 0; j < 8; j++) v[j] = src[j];
        }
        u32 pk[4];
#pragma unroll
        for (int j = 0; j < 4; j++) pk[j] = (u32)f2bf(v[2 * j]) | ((u32)f2bf(v[2 * j + 1]) << 16);
        *(uint4*)&As[r][kc * 8] = *(uint4*)pk;
        *(uint4*)&Bs[r][kc * 8] = *(const uint4*)&wih[(size_t)(n0 + r) * 512 + k];
        __syncthreads();
        bf16x8 af[2], bfr[2];
#pragma unroll
        for (int mi = 0; mi < 2; mi++) af[mi] = *(const bf16x8*)&As[wr * 32 + mi * 16 + (lane & 15)][(lane >> 4) * 8];
#pragma unroll
        for (int ni = 0; ni < 2; ni++) bfr[ni] = *(const bf16x8*)&Bs[wc * 32 + ni * 16 + (lane & 15)][(lane >> 4) * 8];
#pragma unroll
        for (int mi = 0; mi < 2; mi++)
#pragma unroll
            for (int ni = 0; ni < 2; ni++)
                acc[mi][ni] = __builtin_amdgcn_mfma_f32_16x16x32_bf16(af[mi], bfr[ni], acc[mi][ni], 0, 0, 0);
        __syncthreads();
    }
#pragma unroll
    for (int mi = 0; mi < 2; mi++)
#pragma unroll
        for (int ni = 0; ni < 2; ni++) {
            int row = m0 + wr * 32 + mi * 16 + (lane >> 4) * 4;
            int col = n0 + wc * 32 + ni * 16 + (lane & 15);
            float bias = bih[col];
#pragma unroll
            for (int i = 0; i < 4; i++)
                xp[(size_t)(row + i) * GA + col] = f2bf(acc[mi][ni][i] + bias);
        }
}

// ---------------- fused-batch serial GRU ----------------
// All 16 batches in one recurrence. 12 A-WGs (32 units each) + 4 B-WGs (16 B-units each).
// Weights live in VGPRs as MFMA b-fragments. h exchanged via self-tagged u32 words
// (bf16<<16 | step-tag), parity double-buffered, relaxed agent atomics.
__global__ __launch_bounds__(192, 1) void k_serial(
        const float* __restrict__ whhA, const float* __restrict__ bhhA,
        const float* __restrict__ wihB, const float* __restrict__ whhB,
        const float* __restrict__ bhhB, const u16* __restrict__ xp,
        const float* __restrict__ cpart, const float* __restrict__ h0a,
        const float* __restrict__ h0b, u32* hExA, u32* hExB,
        float* __restrict__ yB) {
    __shared__ u16 hbuf[2][16][408];   // hA bf16 [parity][batch][384+24 pad]
    __shared__ u16 xpb[2][3][16][32];  // xp slice [parity][gate][batch][unit]
    __shared__ float pre[96][20];      // A pre-activations [g*32+uu][batch+pad]
    __shared__ u16 hbufB[2][16][80];   // hB bf16 [parity][batch][64+16 pad]
    __shared__ float preY[48][20];
    __shared__ float preH[48][20];
    __shared__ int dead;

    const int blk = blockIdx.x, tid = threadIdx.x;
    const int lane = tid & 63, wv = tid >> 6;  // 3 waves
    const bool isA = (blk < 12);
    const int s = blk;        // A slice: units 32s..32s+32
    const int sB = blk - 12;  // B slice: units 16sB..16sB+16

    // ---- common init: hA(−1) into hbuf[0] ----
    {
        int bb = tid & 15, cc = tid >> 4;  // cc 0..11
#pragma unroll
        for (int i = 0; i < 32; i++)
            hbuf[0][bb][cc * 32 + i] = f2bf(h0a[bb * 384 + cc * 32 + i]);
    }
    if (tid == 0) dead = 0;

    if (isA) {
        // ---- A weights into VGPR fragments ----
        bf16x8 w0[12], w1[12];
        {
            const int c = lane & 15, kq = (lane >> 4) * 8;
#pragma unroll
            for (int K = 0; K < 12; K++) {
                int R0 = wv * 384 + 32 * s + c;
                int R1 = wv * 384 + 32 * s + 16 + c;
                w0[K] = ld_frag_f32(whhA + (size_t)R0 * 384 + K * 32 + kq);
                w1[K] = ld_frag_f32(whhA + (size_t)R1 * 384 + K * 32 + kq);
            }
        }
        // gate-thread state
        float bA0 = 0, bA1 = 0, bA2 = 0;
        float hpr[4] = {0, 0, 0, 0};
        if (tid < 128) {
            int uu = tid & 31, qb = tid >> 5;
            int ug = 32 * s + uu;
            bA0 = bhhA[ug]; bA1 = bhhA[384 + ug]; bA2 = bhhA[768 + ug];
#pragma unroll
            for (int i = 0; i < 4; i++) hpr[i] = h0a[(4 * qb + i) * 384 + ug];
        }
        // xp(0) into xpb[0]
        {
            int g = tid >> 6, bb = (tid >> 2) & 15, q = tid & 3;
#pragma unroll
            for (int i = 0; i < 8; i++)
                xpb[0][g][bb][q * 8 + i] = xp[((size_t)bb * S_LEN) * GA + g * 384 + 32 * s + q * 8 + i];
        }
        __syncthreads();

        for (int t = 0; t < S_LEN; ++t) {
            const int p = t & 1, p2 = p ^ 1;
            const bool pf = (t + 1 < S_LEN);
            // xp(t+1) prefetch issue
            uint4 xpf = make_uint4(0, 0, 0, 0);
            const int pg = tid >> 6, pb = (tid >> 2) & 15, pq = tid & 3;
            if (pf) xpf = *(const uint4*)&xp[((size_t)pb * S_LEN + t + 1) * GA + pg * 384 + 32 * s + pq * 8];
            // matvec: 2 tiles per wave, 12 K-steps
            bf16x8 ah[12];
#pragma unroll
            for (int K = 0; K < 12; K++)
                ah[K] = *(const bf16x8*)&hbuf[p][lane & 15][K * 32 + (lane >> 4) * 8];
            f32x4 aE0 = {0.f, 0.f, 0.f, 0.f}, aO0 = {0.f, 0.f, 0.f, 0.f};
            f32x4 aE1 = {0.f, 0.f, 0.f, 0.f}, aO1 = {0.f, 0.f, 0.f, 0.f};
#pragma unroll
            for (int K = 0; K < 6; K++) {
                aE0 = __builtin_amdgcn_mfma_f32_16x16x32_bf16(ah[2 * K], w0[2 * K], aE0, 0, 0, 0);
                aO0 = __builtin_amdgcn_mfma_f32_16x16x32_bf16(ah[2 * K + 1], w0[2 * K + 1], aO0, 0, 0, 0);
                aE1 = __builtin_amdgcn_mfma_f32_16x16x32_bf16(ah[2 * K], w1[2 * K], aE1, 0, 0, 0);
                aO1 = __builtin_amdgcn_mfma_f32_16x16x32_bf16(ah[2 * K + 1], w1[2 * K + 1], aO1, 0, 0, 0);
            }
            f32x4 d0 = aE0 + aO0, d1 = aE1 + aO1;
            *(f32x4*)&pre[wv * 32 + (lane & 15)][(lane >> 4) * 4] = d0;
            *(f32x4*)&pre[wv * 32 + 16 + (lane & 15)][(lane >> 4) * 4] = d1;
            __syncthreads();  // B1
            if (pf) *(uint4*)&xpb[p2][pg][pb][pq * 8] = xpf;
            // gates
            if (tid < 128) {
                int uu = tid & 31, qb = tid >> 5;
                f32x4 vr = *(const f32x4*)&pre[uu][qb * 4];
                f32x4 vz = *(const f32x4*)&pre[32 + uu][qb * 4];
                f32x4 vn = *(const f32x4*)&pre[64 + uu][qb * 4];
#pragma unroll
                for (int i = 0; i < 4; i++) {
                    int bb = 4 * qb + i;
                    float xr = bf2f(xpb[p][0][bb][uu]);
                    float xz = bf2f(xpb[p][1][bb][uu]);
                    float xn = bf2f(xpb[p][2][bb][uu]);
                    float rg = sigm(xr + vr[i] + bA0);
                    float zg = sigm(xz + vz[i] + bA1);
                    float ng = tanh_(xn + rg * (vn[i] + bA2));
                    float hnew = (1.f - zg) * ng + zg * hpr[i];
                    hpr[i] = hnew;
                    ast32(hExA + p2 * 6144 + bb * 384 + 32 * s + uu,
                          ((u32)f2bf(hnew) << 16) | (u32)(t + 1));
                }
            }
            // poll + unpack hA(t) for next step
            if (pf) {
                bool dd = (dead != 0);
                int bb = tid & 15, cc = tid >> 4;
                const u64* src = (const u64*)(hExA + p2 * 6144) + bb * 192 + cc * 16;
                const u32 tg = (u32)(t + 1);
                u64 v[16];
#pragma unroll
                for (int i = 0; i < 16; i++) v[i] = ald64(src + i);
                if (!dd) {
#pragma unroll
                    for (int i = 0; i < 16; i++) {
                        int cnt = 0;
                        while (((u32)v[i] & 0xffffu) != tg || ((u32)(v[i] >> 32) & 0xffffu) != tg) {
                            v[i] = ald64(src + i);
                            if (++cnt > CAPP) { dead = 1; break; }
                        }
                    }
                }
                u32 ow[16];
#pragma unroll
                for (int i = 0; i < 16; i++)
                    ow[i] = ((u32)v[i] >> 16) | ((u32)(v[i] >> 32) & 0xffff0000u);
                u16* dst = &hbuf[p2][bb][cc * 32];
#pragma unroll
                for (int i = 0; i < 4; i++) *(uint4*)&dst[i * 8] = *(uint4*)&ow[i * 4];
            }
            __syncthreads();  // B2
        }
    } else {
        // ================= B-WG =================
        bf16x8 wy[12], wh[2];
        {
            const int c = lane & 15, kq = (lane >> 4) * 8;
            int R = wv * 64 + 16 * sB + c;
#pragma unroll
            for (int K = 0; K < 12; K++)
                wy[K] = ld_frag_f32(wihB + (size_t)R * 512 + K * 32 + kq);
#pragma unroll
            for (int K = 0; K < 2; K++)
                wh[K] = ld_frag_f32(whhB + (size_t)R * 64 + K * 32 + kq);
        }
        float bB0 = 0, bB1 = 0, bB2 = 0;
        float hprB[2] = {0, 0};
        if (tid < 128) {
            int uu = tid & 15, j = tid >> 4;
            int ug = 16 * sB + uu;
            bB0 = bhhB[ug]; bB1 = bhhB[64 + ug]; bB2 = bhhB[128 + ug];
            hprB[0] = h0b[(2 * j) * 64 + ug];
            hprB[1] = h0b[(2 * j + 1) * 64 + ug];
        }
        if (tid < 64) {
            int bb = tid & 15, q = tid >> 4;
#pragma unroll
            for (int i = 0; i < 16; i++)
                hbufB[1][bb][16 * q + i] = f2bf(h0b[bb * 64 + 16 * q + i]);
        }
        __syncthreads();

        for (int t = 0; t <= S_LEN; ++t) {
            const int p = t & 1, p2 = p ^ 1;
            float cpv[6] = {0, 0, 0, 0, 0, 0};
            if (t >= 1 && tid < 128) {
                int uu = tid & 15, j = tid >> 4, fr = (t - 1) / 160;
#pragma unroll
                for (int g = 0; g < 3; g++)
#pragma unroll
                    for (int i = 0; i < 2; i++)
                        cpv[g * 2 + i] = cpart[((size_t)(2 * j + i) * 32 + fr) * 192 + g * 64 + 16 * sB + uu];
            }
            if (t >= 1) {
                bf16x8 ah[12];
#pragma unroll
                for (int K = 0; K < 12; K++)
                    ah[K] = *(const bf16x8*)&hbuf[p][lane & 15][K * 32 + (lane >> 4) * 8];
                f32x4 yE = {0.f, 0.f, 0.f, 0.f}, yO = {0.f, 0.f, 0.f, 0.f};
#pragma unroll
                for (int K = 0; K < 6; K++) {
                    yE = __builtin_amdgcn_mfma_f32_16x16x32_bf16(ah[2 * K], wy[2 * K], yE, 0, 0, 0);
                    yO = __builtin_amdgcn_mfma_f32_16x16x32_bf16(ah[2 * K + 1], wy[2 * K + 1], yO, 0, 0, 0);
                }
                f32x4 dy = yE + yO;
                bf16x8 bh0 = *(const bf16x8*)&hbufB[p][lane & 15][(lane >> 4) * 8];
                bf16x8 bh1 = *(const bf16x8*)&hbufB[p][lane & 15][32 + (lane >> 4) * 8];
                f32x4 dh = {0.f, 0.f, 0.f, 0.f};
                dh = __builtin_amdgcn_mfma_f32_16x16x32_bf16(bh0, wh[0], dh, 0, 0, 0);
                dh = __builtin_amdgcn_mfma_f32_16x16x32_bf16(bh1, wh[1], dh, 0, 0, 0);
                *(f32x4*)&preY[wv * 16 + (lane & 15)][(lane >> 4) * 4] = dy;
                *(f32x4*)&preH[wv * 16 + (lane & 15)][(lane >> 4) * 4] = dh;
            }
            __syncthreads();  // B1
            if (t >= 1 && tid < 128) {
                int uu = tid & 15, j = tid >> 4;
                int ug = 16 * sB + uu;
                float2 vy[3], vh[3];
#pragma unroll
                for (int g = 0; g < 3; g++) {
                    vy[g] = *(const float2*)&preY[g * 16 + uu][2 * j];
                    vh[g] = *(const float2*)&preH[g * 16 + uu][2 * j];
                }
#pragma unroll
                for (int i = 0; i < 2; i++) {
                    int bb = 2 * j + i;
                    float xr = (i ? vy[0].y : vy[0].x) + cpv[0 + i];
                    float xz = (i ? vy[1].y : vy[1].x) + cpv[2 + i];
                    float xn = (i ? vy[2].y : vy[2].x) + cpv[4 + i];
                    float hr = (i ? vh[0].y : vh[0].x) + bB0;
                    float hz = (i ? vh[1].y : vh[1].x) + bB1;
                    float hn = (i ? vh[2].y : vh[2].x) + bB2;
                    float rg = sigm(xr + hr);
                    float zg = sigm(xz + hz);
                    float ng = tanh_(xn + rg * hn);
                    float hnew = (1.f - zg) * ng + zg * hprB[i];
                    hprB[i] = hnew;
                    yB[((size_t)bb * S_LEN + (t - 1)) * UB + ug] = hnew;
                    if (t < S_LEN)
                        ast32(hExB + p2 * 1024 + bb * 64 + ug,
                              ((u32)f2bf(hnew) << 16) | (u32)(t + 1));
                }
            }
            if (t < S_LEN) {
                bool dd = (dead != 0);
                const u32 tg = (u32)(t + 1);
                // poll hA
                {
                    int bb = tid & 15, cc = tid >> 4;
                    const u64* src = (const u64*)(hExA + p2 * 6144) + bb * 192 + cc * 16;
                    u64 v[16];
#pragma unroll
                    for (int i = 0; i < 16; i++) v[i] = ald64(src + i);
                    if (!dd) {
#pragma unroll
                        for (int i = 0; i < 16; i++) {
                            int cnt = 0;
                            while (((u32)v[i] & 0xffffu) != tg || ((u32)(v[i] >> 32) & 0xffffu) != tg) {
                                v[i] = ald64(src + i);
                                if (++cnt > CAPP) { dead = 1; break; }
                            }
                        }
                    }
                    u32 ow[16];
#pragma unroll
                    for (int i = 0; i < 16; i++)
                        ow[i] = ((u32)v[i] >> 16) | ((u32)(v[i] >> 32) & 0xffff0000u);
                    u16* dst = &hbuf[p2][bb][cc * 32];
#pragma unroll
                    for (int i = 0; i < 4; i++) *(uint4*)&dst[i * 8] = *(uint4*)&ow[i * 4];
                }
                // poll hB
                if (t >= 1 && tid < 64) {
                    int bb = tid & 15, q = tid >> 4;
                    const u64* src = (const u64*)(hExB + p2 * 1024) + bb * 32 + q * 8;
                    u64 v[8];
#pragma unroll
                    for (int i = 0; i < 8; i++) v[i] = ald64(src + i);
                    if (!dd) {
#pragma unroll
                        for (int i = 0; i < 8; i++) {
                            int cnt = 0;
                            while (((u32)v[i] & 0xffffu) != tg || ((u32)(v[i] >> 32) & 0xffffu) != tg) {
                                v[i] = ald64(src + i);
                                if (++cnt > CAPP) { dead = 1; break; }
                            }
                        }
                    }
                    u32 ow[8];
#pragma unroll
                    for (int i = 0; i < 8; i++)
                        ow[i] = ((u32)v[i] >> 16) | ((u32)(v[i] >> 32) & 0xffff0000u);
                    u16* dst = &hbufB[p2][bb][16 * q];
#pragma unroll
                    for (int i = 0; i < 2; i++) *(uint4*)&dst[i * 8] = *(uint4*)&ow[i * 4];
                }
            }
            __syncthreads();  // B2
        }
    }
}

// ---------------- dual FC + log_softmax ----------------
__global__ __launch_bounds__(256) void k_fc(const float* __restrict__ yB, const float* __restrict__ w1,
                                            const float* __restrict__ b1, const float* __restrict__ w2,
                                            const float* __restrict__ b2, const float* __restrict__ alpha,
                                            const float* __restrict__ beta, float* __restrict__ out) {
    __shared__ float yb[4][64];
    __shared__ float vb[4][256];
    int tid = threadIdx.x;
    size_t r0 = (size_t)blockIdx.x * 4;
    { int r = tid >> 6, k = tid & 63; yb[r][k] = yB[(r0 + r) * 64 + k]; }
    __syncthreads();
    int o = tid;
    float a1[4] = {0, 0, 0, 0}, a2[4] = {0, 0, 0, 0};
    for (int k = 0; k < 64; k += 4) {
        float4 u = *(const float4*)(w1 + o * 64 + k);
        float4 v = *(const float4*)(w2 + o * 64 + k);
#pragma unroll
        for (int r = 0; r < 4; r++) {
            float y0 = yb[r][k], y1 = yb[r][k + 1], y2 = yb[r][k + 2], y3 = yb[r][k + 3];
            a1[r] = fmaf(u.x, y0, fmaf(u.y, y1, fmaf(u.z, y2, fmaf(u.w, y3, a1[r]))));
            a2[r] = fmaf(v.x, y0, fmaf(v.y, y1, fmaf(v.z, y2, fmaf(v.w, y3, a2[r]))));
        }
    }
    float al = alpha[o], be = beta[o], c1 = b1[o], c2 = b2[o];
#pragma unroll
    for (int r = 0; r < 4; r++)
        vb[r][o] = al * tanh_(a1[r] + c1) + be * tanh_(a2[r] + c2);
    __syncthreads();
    int wv = tid >> 6, l = tid & 63;
    float x0 = vb[wv][l], x1 = vb[wv][64 + l], x2 = vb[wv][128 + l], x3 = vb[wv][192 + l];
    float m = fmaxf(fmaxf(x0, x1), fmaxf(x2, x3));
#pragma unroll
    for (int off = 1; off < 64; off <<= 1) m = fmaxf(m, __shfl_xor(m, off));
    float sum = __expf(x0 - m) + __expf(x1 - m) + __expf(x2 - m) + __expf(x3 - m);
#pragma unroll
    for (int off = 1; off < 64; off <<= 1) sum += __shfl_xor(sum, off);
    float lse = m + __logf(sum);
    float* po = out + (r0 + wv) * 256;
    po[l] = x0 - lse;
    po[64 + l] = x1 - lse;
    po[128 + l] = x2 - lse;
    po[192 + l] = x3 - lse;
}

extern "C" void kernel_launch(void* const* d_in, const int* in_sizes, int n_in,
                              void* d_out, int out_size, void* d_ws, size_t ws_size,
                              hipStream_t stream) {
    const float* features = (const float*)d_in[0];
    const int* periods = (const int*)d_in[1];
    const int* signals = (const int*)d_in[2];
    const float* gruA0 = (const float*)d_in[3];
    const float* gruB0 = (const float*)d_in[4];
    const float* period_emb = (const float*)d_in[5];
    const float* signal_emb = (const float*)d_in[6];
    const float* conv1_w = (const float*)d_in[7];
    const float* conv1_b = (const float*)d_in[8];
    const float* conv2_w = (const float*)d_in[9];
    const float* conv2_b = (const float*)d_in[10];
    const float* fd1_w = (const float*)d_in[11];
    const float* fd1_b = (const float*)d_in[12];
    const float* fd2_w = (const float*)d_in[13];
    const float* fd2_b = (const float*)d_in[14];
    const float* grua_wih = (const float*)d_in[15];
    const float* grua_whh = (const float*)d_in[16];
    const float* grua_bih = (const float*)d_in[17];
    const float* grua_bhh = (const float*)d_in[18];
    const float* grub_wih = (const float*)d_in[19];
    const float* grub_whh = (const float*)d_in[20];
    const float* grub_bih = (const float*)d_in[21];
    const float* grub_bhh = (const float*)d_in[22];
    const float* fc1_w = (const float*)d_in[23];
    const float* fc1_b = (const float*)d_in[24];
    const float* fc2_w = (const float*)d_in[25];
    const float* fc2_b = (const float*)d_in[26];
    const float* alpha = (const float*)d_in[27];
    const float* beta = (const float*)d_in[28];
    float* out = (float*)d_out;

    char* ws = (char*)d_ws;
    size_t off = 0;
    auto alloc = [&](size_t bytes) { void* p = ws + off; off += (bytes + 255) & ~(size_t)255; return p; };
    u16* xp = (u16*)alloc((size_t)16 * 5120 * 1152 * 2);
    u16* wihA = (u16*)alloc((size_t)1152 * 512 * 2);
    float* c1 = (float*)alloc((size_t)16 * 34 * 128 * 4);
    float* c2 = (float*)alloc((size_t)16 * 32 * 128 * 4);
    float* cc = (float*)alloc((size_t)16 * 32 * 128 * 4);
    float* cpart = (float*)alloc((size_t)16 * 32 * 192 * 4);
    float* yB = (float*)alloc((size_t)16 * 5120 * 64 * 4);
    u32* hExA = (u32*)alloc((size_t)2 * 6144 * 4);
    u32* hExB = (u32*)alloc((size_t)2 * 1024 * 4);

    k_cvt<<<dim3(2304), dim3(256), 0, stream>>>(grua_wih, wihA);
    k_frame1<<<dim3(34, 16), dim3(128), 0, stream>>>(features, periods, period_emb, conv1_w, conv1_b, c1);
    k_frame2<<<dim3(32, 16), dim3(128), 0, stream>>>(c1, conv2_w, conv2_b, c2);
    k_fd<<<dim3(32, 16), dim3(128), 0, stream>>>(c2, fd1_w, fd1_b, fd2_w, fd2_b, cc);
    k_cpart<<<dim3(32, 16), dim3(192), 0, stream>>>(cc, grub_wih, grub_bih, cpart);
    k_init<<<dim3(56), dim3(256), 0, stream>>>(hExA);  // zeroes hExA (48KB) + hExB (8KB) contiguously
    k_gemm<<<dim3(1280, 18), dim3(256), 0, stream>>>(signals, signal_emb, cc, wihA, grua_bih, xp);
    k_serial<<<dim3(16), dim3(192), 0, stream>>>(grua_whh, grua_bhh, grub_wih, grub_whh, grub_bhh,
                                                 xp, cpart, gruA0, gruB0, hExA, hExB, yB);
    k_fc<<<dim3(20480), dim3(256), 0, stream>>>(yB, fc1_w, fc1_b, fc2_w, fc2_b, alpha, beta, out);
}

// Round 6
// 11279.173 us; speedup vs baseline: 8.5706x; 3.8239x over previous
//
#include <hip/hip_runtime.h>

typedef unsigned short u16;
typedef unsigned int u32;
typedef unsigned long long u64;
typedef __attribute__((ext_vector_type(8))) short bf16x8;
typedef __attribute__((ext_vector_type(4))) float f32x4;

#define S_LEN 5120
#define UB 64
#define GA 1152
#define CAPP (1 << 16)

__device__ __forceinline__ float bf2f(u16 u) { return __uint_as_float(((u32)u) << 16); }
__device__ __forceinline__ u16 f2bf(float f) {
    u32 x = __float_as_uint(f);
    return (u16)((x + 0x7fffu + ((x >> 16) & 1u)) >> 16);
}
__device__ __forceinline__ float blo(u32 w) { return __uint_as_float(w << 16); }
__device__ __forceinline__ float bhi(u32 w) { return __uint_as_float(w & 0xffff0000u); }
__device__ __forceinline__ float sigm(float x) { return 1.f / (1.f + __expf(-x)); }
__device__ __forceinline__ float tanh_(float x) { float e = __expf(2.f * x); return 1.f - 2.f / (e + 1.f); }

#if __has_builtin(__builtin_amdgcn_fdot2)
typedef _Float16 h2v __attribute__((ext_vector_type(2)));
__device__ __forceinline__ float dot2p(u32 w, u32 h, float acc) {
    return __builtin_amdgcn_fdot2(__builtin_bit_cast(h2v, w), __builtin_bit_cast(h2v, h), acc, false);
}
__device__ __forceinline__ u32 packpair(float a, float b) {
    u16 x = __builtin_bit_cast(u16, (_Float16)a);
    u16 y = __builtin_bit_cast(u16, (_Float16)b);
    return (u32)x | ((u32)y << 16);
}
__device__ __forceinline__ u16 pack1(float a) { return __builtin_bit_cast(u16, (_Float16)a); }
#else
__device__ __forceinline__ float dot2p(u32 w, u32 h, float acc) {
    acc = fmaf(blo(w), blo(h), acc);
    return fmaf(bhi(w), bhi(h), acc);
}
__device__ __forceinline__ u32 packpair(float a, float b) { return (u32)f2bf(a) | ((u32)f2bf(b) << 16); }
__device__ __forceinline__ u16 pack1(float a) { return f2bf(a); }
#endif

__device__ __forceinline__ u64 ald64(const u64* p) {
    return __hip_atomic_load(p, __ATOMIC_RELAXED, __HIP_MEMORY_SCOPE_AGENT);
}
__device__ __forceinline__ u32 ald32(const u32* p) {
    return __hip_atomic_load(p, __ATOMIC_RELAXED, __HIP_MEMORY_SCOPE_AGENT);
}
__device__ __forceinline__ void ast32(u32* p, u32 v) {
    __hip_atomic_store(p, v, __ATOMIC_RELAXED, __HIP_MEMORY_SCOPE_AGENT);
}

// ---------------- convert grua_wih to bf16 ----------------
__global__ __launch_bounds__(256) void k_cvt(const float* __restrict__ src, u16* __restrict__ dst) {
    int i = blockIdx.x * 256 + threadIdx.x;
    dst[i] = f2bf(src[i]);
}

// ---------------- frame-rate network ----------------
__global__ __launch_bounds__(128) void k_frame1(const float* __restrict__ features, const int* __restrict__ periods,
                                                const float* __restrict__ pemb, const float* __restrict__ w,
                                                const float* __restrict__ bias, float* __restrict__ c1) {
    __shared__ float fin[3][84];
    int t = blockIdx.x, b = blockIdx.y, o = threadIdx.x;
    for (int i = threadIdx.x; i < 252; i += 128) {
        int kk = i / 84, ci = i % 84, tt = t + kk;
        float v;
        if (ci < 20) v = features[(b * 36 + tt) * 20 + ci];
        else v = pemb[periods[b * 36 + tt] * 64 + (ci - 20)];
        fin[kk][ci] = v;
    }
    __syncthreads();
    float acc = bias[o];
    for (int kk = 0; kk < 3; kk++)
        for (int ci = 0; ci < 84; ci++)
            acc = fmaf(fin[kk][ci], w[o * 252 + ci * 3 + kk], acc);
    c1[(b * 34 + t) * 128 + o] = tanh_(acc);
}

__global__ __launch_bounds__(128) void k_frame2(const float* __restrict__ c1, const float* __restrict__ w,
                                                const float* __restrict__ bias, float* __restrict__ c2) {
    __shared__ float fin[3][128];
    int t = blockIdx.x, b = blockIdx.y, o = threadIdx.x;
    for (int i = threadIdx.x; i < 384; i += 128) {
        int kk = i >> 7, ci = i & 127;
        fin[kk][ci] = c1[(b * 34 + t + kk) * 128 + ci];
    }
    __syncthreads();
    float acc = bias[o];
    for (int kk = 0; kk < 3; kk++)
        for (int ci = 0; ci < 128; ci++)
            acc = fmaf(fin[kk][ci], w[o * 384 + ci * 3 + kk], acc);
    c2[(b * 32 + t) * 128 + o] = tanh_(acc);
}

__global__ __launch_bounds__(128) void k_fd(const float* __restrict__ c2, const float* __restrict__ w1,
                                            const float* __restrict__ b1, const float* __restrict__ w2,
                                            const float* __restrict__ b2, float* __restrict__ cc) {
    __shared__ float a0[128], a1s[128];
    int t = blockIdx.x, b = blockIdx.y, o = threadIdx.x;
    a0[o] = c2[(b * 32 + t) * 128 + o];
    __syncthreads();
    float acc = b1[o];
    for (int k = 0; k < 128; k++) acc = fmaf(a0[k], w1[o * 128 + k], acc);
    a1s[o] = tanh_(acc);
    __syncthreads();
    float acc2 = b2[o];
    for (int k = 0; k < 128; k++) acc2 = fmaf(a1s[k], w2[o * 128 + k], acc2);
    cc[(b * 32 + t) * 128 + o] = tanh_(acc2);
}

// cpart[b][fr][192] = grub_wih[:,384:512] @ c[b][fr] + grub_bih
__global__ __launch_bounds__(192) void k_cpart(const float* __restrict__ cc, const float* __restrict__ wihB,
                                               const float* __restrict__ bihB, float* __restrict__ cpart) {
    __shared__ float cl[128];
    int fr = blockIdx.x, b = blockIdx.y, o = threadIdx.x;
    if (o < 128) cl[o] = cc[(b * 32 + fr) * 128 + o];
    __syncthreads();
    float acc = bihB[o];
    for (int k = 0; k < 128; k++) acc = fmaf(cl[k], wihB[o * 512 + 384 + k], acc);
    cpart[((size_t)b * 32 + fr) * 192 + o] = acc;
}

// ---------------- init: clear stale tags in exchange ring + bprog ----------------
__global__ __launch_bounds__(256) void k_init(u32* hEx) {
    hEx[blockIdx.x * 256 + threadIdx.x] = 0u;
}

// ---------------- GRU-A input projection GEMM ----------------
__global__ __launch_bounds__(256) void k_gemm(const int* __restrict__ signals, const float* __restrict__ semb,
                                              const float* __restrict__ c, const u16* __restrict__ wih,
                                              const float* __restrict__ bih, u16* __restrict__ xp) {
    __shared__ u16 As[64][40];
    __shared__ u16 Bs[64][40];
    int m0 = blockIdx.x * 64, n0 = blockIdx.y * 64;
    int tid = threadIdx.x;
    int r = tid >> 2, kc = tid & 3;
    int lane = tid & 63, wv = tid >> 6;
    int wr = wv >> 1, wc = wv & 1;
    int mrow = m0 + r;
    int b = mrow / S_LEN, s = mrow % S_LEN;
    const int* sigrow = signals + mrow * 3;
    const float* crow = c + ((size_t)(b * 32) + s / 160) * 128;
    f32x4 acc[2][2];
#pragma unroll
    for (int i = 0; i < 2; i++)
#pragma unroll
        for (int j = 0; j < 2; j++) { acc[i][j][0] = 0.f; acc[i][j][1] = 0.f; acc[i][j][2] = 0.f; acc[i][j][3] = 0.f; }
    for (int k0 = 0; k0 < 512; k0 += 32) {
        int k = k0 + kc * 8;
        float v[8];
        if (k < 384) {
            int idx = sigrow[k >> 7];
            const float* src = semb + idx * 128 + (k & 127);
#pragma unroll
            for (int j = 0; j < 8; j++) v[j] = src[j];
        } else {
            const float* src = crow + (k - 384);
#pragma unroll
            for (int j = 0; j < 8; j++) v[j] = src[j];
        }
        u32 pk[4];
#pragma unroll
        for (int j = 0; j < 4; j++) pk[j] = (u32)f2bf(v[2 * j]) | ((u32)f2bf(v[2 * j + 1]) << 16);
        *(uint4*)&As[r][kc * 8] = *(uint4*)pk;
        *(uint4*)&Bs[r][kc * 8] = *(const uint4*)&wih[(size_t)(n0 + r) * 512 + k];
        __syncthreads();
        bf16x8 af[2], bfr[2];
#pragma unroll
        for (int mi = 0; mi < 2; mi++) af[mi] = *(const bf16x8*)&As[wr * 32 + mi * 16 + (lane & 15)][(lane >> 4) * 8];
#pragma unroll
        for (int ni = 0; ni < 2; ni++) bfr[ni] = *(const bf16x8*)&Bs[wc * 32 + ni * 16 + (lane & 15)][(lane >> 4) * 8];
#pragma unroll
        for (int mi = 0; mi < 2; mi++)
#pragma unroll
            for (int ni = 0; ni < 2; ni++)
                acc[mi][ni] = __builtin_amdgcn_mfma_f32_16x16x32_bf16(af[mi], bfr[ni], acc[mi][ni], 0, 0, 0);
        __syncthreads();
    }
#pragma unroll
    for (int mi = 0; mi < 2; mi++)
#pragma unroll
        for (int ni = 0; ni < 2; ni++) {
            int row = m0 + wr * 32 + mi * 16 + (lane >> 4) * 4;
            int col = n0 + wc * 32 + ni * 16 + (lane & 15);
            float bias = bih[col];
#pragma unroll
            for (int i = 0; i < 4; i++)
                xp[(size_t)(row + i) * GA + col] = f2bf(acc[mi][ni][i] + bias);
        }
}

// ---------------- serial GRU: 4 WGs/batch (3x A-slice + 1x B), minimal 1-hop exchange ----------------
// hEx ring: u32 [b][slot 0..7][slice 0..2][128 units], word = (f16(h) << 16) | (t+1)
// bprog: u32[16] at hEx + 49152.
__global__ __launch_bounds__(512) void k_serial(
        const float* __restrict__ whhA, const float* __restrict__ bhhA,
        const float* __restrict__ wihB, const float* __restrict__ whhB,
        const float* __restrict__ bhhB, const u16* __restrict__ xp,
        const float* __restrict__ cpart, const float* __restrict__ h0a,
        const float* __restrict__ h0b, u32* hEx, u32* bprog,
        float* __restrict__ yB) {
    const int blk = blockIdx.x, tid = threadIdx.x;
    const int b = blk >> 2, role = blk & 3;

    if (role < 3) {
        // ================= A-WG: units 128*role .. +128 =================
        __shared__ __align__(16) u32 hbuf[2][192];  // hA as f16 pairs, parity
        __shared__ float red[384][5];               // [row][kc] padded
        __shared__ u16 xpb[2][384];                 // xp rows for this WG, parity
        __shared__ int lbB, deadf;
        const int s = role;
        const int u = tid & 127, kc = tid >> 7;     // matvec role for tid<384
        // weights: 3 rows (u, 128+u, 256+u) x K-third [128*kc, +128) -> 192 packed u32
        u32 w[3][64];
        if (tid < 384) {
#pragma unroll
            for (int g = 0; g < 3; g++) {
                const float* wr = whhA + ((size_t)(g * 384 + s * 128 + u)) * 384 + kc * 128;
#pragma unroll
                for (int c = 0; c < 16; c++)
#pragma unroll
                    for (int j = 0; j < 4; j++)
                        w[g][c * 4 + j] = packpair(wr[c * 8 + 2 * j], wr[c * 8 + 2 * j + 1]);
            }
        }
        if (tid < 192) hbuf[0][tid] = packpair(h0a[b * 384 + 2 * tid], h0a[b * 384 + 2 * tid + 1]);
        const int xcol = (tid >> 7) * 384 + s * 128 + (tid & 127);  // row tid -> xp column
        float hprA = 0, bh0 = 0, bh1 = 0, bh2 = 0;
        if (tid < 128) {
            hprA = h0a[b * 384 + s * 128 + tid];
            bh0 = bhhA[s * 128 + tid];
            bh1 = bhhA[384 + s * 128 + tid];
            bh2 = bhhA[768 + s * 128 + tid];
        }
        if (tid < 384) xpb[0][tid] = xp[((size_t)b * S_LEN) * GA + xcol];
        if (tid == 0) { lbB = 0; deadf = 0; }
        __syncthreads();

        for (int t = 0; t < S_LEN; ++t) {
            const int p = t & 1, p2 = p ^ 1;
            u16 xnext = 0;
            int lbn = -1;
            // PHASE1: pollers fetch peers' h(t-1); matvec threads issue xp(t+1)
            if (tid < 384) {
                if (t + 1 < S_LEN) xnext = xp[((size_t)b * S_LEN + t + 1) * GA + xcol];
                if (tid == 0) lbn = (int)ald32(bprog + b);
            } else if (t > 0) {
                const int i = tid - 384, pi = i >> 6, idx = i & 63;
                const int ps = pi + (pi >= s ? 1 : 0);
                const u64* src = (const u64*)hEx + (((size_t)b * 8 + ((t - 1) & 7)) * 3 + ps) * 64 + idx;
                const u32 tg = (u32)t & 0xffffu;
                u64 v = ald64(src);
                int cnt = 0;
                while ((((u32)v) & 0xffffu) != tg || (((u32)(v >> 32)) & 0xffffu) != tg) {
                    if (deadf || ++cnt > CAPP) { deadf = 1; break; }
                    v = ald64(src);
                }
                hbuf[p][ps * 64 + idx] = (((u32)v) >> 16) | (((u32)(v >> 32)) & 0xffff0000u);
            }
            __syncthreads();  // S1
            // PHASE2: matvec
            if (tid < 384) {
                const uint4* hb4 = (const uint4*)&hbuf[p][0] + kc * 16;
                float a00 = 0, a01 = 0, a10 = 0, a11 = 0, a20 = 0, a21 = 0;
#pragma unroll
                for (int c = 0; c < 16; c++) {
                    uint4 hc = hb4[c];
                    a00 = dot2p(w[0][4 * c + 0], hc.x, a00); a01 = dot2p(w[0][4 * c + 1], hc.y, a01);
                    a00 = dot2p(w[0][4 * c + 2], hc.z, a00); a01 = dot2p(w[0][4 * c + 3], hc.w, a01);
                    a10 = dot2p(w[1][4 * c + 0], hc.x, a10); a11 = dot2p(w[1][4 * c + 1], hc.y, a11);
                    a10 = dot2p(w[1][4 * c + 2], hc.z, a10); a11 = dot2p(w[1][4 * c + 3], hc.w, a11);
                    a20 = dot2p(w[2][4 * c + 0], hc.x, a20); a21 = dot2p(w[2][4 * c + 1], hc.y, a21);
                    a20 = dot2p(w[2][4 * c + 2], hc.z, a20); a21 = dot2p(w[2][4 * c + 3], hc.w, a21);
                }
                red[u][kc] = a00 + a01;
                red[128 + u][kc] = a10 + a11;
                red[256 + u][kc] = a20 + a21;
                if (t + 1 < S_LEN) xpb[p2][tid] = xnext;
                if (tid == 0 && lbn >= 0) lbB = lbn;
            }
            __syncthreads();  // S2
            // PHASE3: gates + publish
            if (tid < 128) {
                if (t - 7 > lbB && !deadf) {
                    int cnt = 0;
                    while ((int)ald32(bprog + b) < t - 7) {
                        if (++cnt > CAPP) { deadf = 1; break; }
                    }
                }
                float pr = red[tid][0] + red[tid][1] + red[tid][2] + bh0;
                float pz = red[128 + tid][0] + red[128 + tid][1] + red[128 + tid][2] + bh1;
                float pn = red[256 + tid][0] + red[256 + tid][1] + red[256 + tid][2] + bh2;
                float rg = sigm(bf2f(xpb[p][tid]) + pr);
                float zg = sigm(bf2f(xpb[p][128 + tid]) + pz);
                float ng = tanh_(bf2f(xpb[p][256 + tid]) + rg * pn);
                float hnew = (1.f - zg) * ng + zg * hprA;
                hprA = hnew;
                u16 hb16 = pack1(hnew);
                ((u16*)&hbuf[p2][0])[s * 128 + tid] = hb16;
                ast32(hEx + (((size_t)b * 8 + (t & 7)) * 3 + s) * 128 + tid,
                      ((u32)hb16 << 16) | (u32)(t + 1));
            }
            // next S1 provides ordering
        }
    } else {
        // ================= B-WG: all 64 GRU-B units, hB fully local =================
        __shared__ __align__(16) u32 hbufA[2][192];
        __shared__ __align__(16) u16 hbB[2][64];
        __shared__ float redy[192][3];
        __shared__ float redh[192];
        __shared__ float cpl[32][192];
        __shared__ int deadB;
        const int r = (tid < 192) ? tid : tid - 192;
        const int kh = (tid < 192) ? 0 : 1;
        u32 wy[96];
        if (tid < 384) {
            const float* wr = wihB + (size_t)r * 512 + kh * 192;
#pragma unroll
            for (int i = 0; i < 96; i++) wy[i] = packpair(wr[2 * i], wr[2 * i + 1]);
        }
        u32 wb0[32], wb1[32];
        if (tid >= 384 && tid < 480) {
            const int rb = (tid - 384) * 2;
            const float* w0p = whhB + (size_t)rb * 64;
            const float* w1p = whhB + (size_t)(rb + 1) * 64;
#pragma unroll
            for (int i = 0; i < 32; i++) {
                wb0[i] = packpair(w0p[2 * i], w0p[2 * i + 1]);
                wb1[i] = packpair(w1p[2 * i], w1p[2 * i + 1]);
            }
        }
        for (int i = tid; i < 32 * 192; i += 512)
            cpl[i / 192][i % 192] = cpart[((size_t)b * 32) * 192 + i];
        float bB0 = 0, bB1 = 0, bB2 = 0, hprB = 0;
        if (tid < 64) {
            bB0 = bhhB[tid]; bB1 = bhhB[64 + tid]; bB2 = bhhB[128 + tid];
            hprB = h0b[b * 64 + tid];
            hbB[0][tid] = pack1(hprB);
        }
        if (tid == 0) deadB = 0;
        __syncthreads();

        for (int tb = 0; tb < S_LEN; ++tb) {
            const int p = tb & 1, p2 = p ^ 1;
            // PHASE1: poll hA(tb)
            if (tid < 192) {
                const int ps = tid >> 6, idx = tid & 63;
                const u64* src = (const u64*)hEx + (((size_t)b * 8 + (tb & 7)) * 3 + ps) * 64 + idx;
                const u32 tg = (u32)(tb + 1) & 0xffffu;
                u64 v = ald64(src);
                int cnt = 0;
                while ((((u32)v) & 0xffffu) != tg || (((u32)(v >> 32)) & 0xffffu) != tg) {
                    if (deadB || ++cnt > CAPP) { deadB = 1; break; }
                    v = ald64(src);
                }
                hbufA[p][ps * 64 + idx] = (((u32)v) >> 16) | (((u32)(v >> 32)) & 0xffff0000u);
            }
            __syncthreads();  // S1
            // PHASE2: matvecs
            if (tid < 384) {
                const uint4* hb4 = (const uint4*)&hbufA[p][0] + kh * 24;
                float a0 = 0, a1 = 0;
#pragma unroll
                for (int c = 0; c < 24; c++) {
                    uint4 hc = hb4[c];
                    a0 = dot2p(wy[4 * c + 0], hc.x, a0); a1 = dot2p(wy[4 * c + 1], hc.y, a1);
                    a0 = dot2p(wy[4 * c + 2], hc.z, a0); a1 = dot2p(wy[4 * c + 3], hc.w, a1);
                }
                redy[r][kh] = a0 + a1;
            } else if (tid < 480) {
                const uint4* hb4 = (const uint4*)&hbB[p][0];
                float a0 = 0, b0 = 0;
#pragma unroll
                for (int q = 0; q < 8; q++) {
                    uint4 hc = hb4[q];
                    a0 = dot2p(wb0[4 * q + 0], hc.x, a0); a0 = dot2p(wb0[4 * q + 1], hc.y, a0);
                    a0 = dot2p(wb0[4 * q + 2], hc.z, a0); a0 = dot2p(wb0[4 * q + 3], hc.w, a0);
                    b0 = dot2p(wb1[4 * q + 0], hc.x, b0); b0 = dot2p(wb1[4 * q + 1], hc.y, b0);
                    b0 = dot2p(wb1[4 * q + 2], hc.z, b0); b0 = dot2p(wb1[4 * q + 3], hc.w, b0);
                }
                const int rb = (tid - 384) * 2;
                redh[rb] = a0;
                redh[rb + 1] = b0;
            }
            __syncthreads();  // S2
            // PHASE3: gates + yB + progress
            if (tid < 64) {
                const int fr = tb / 160;
                float xr = redy[tid][0] + redy[tid][1] + cpl[fr][tid];
                float xz = redy[64 + tid][0] + redy[64 + tid][1] + cpl[fr][64 + tid];
                float xn = redy[128 + tid][0] + redy[128 + tid][1] + cpl[fr][128 + tid];
                float hr = redh[tid] + bB0;
                float hz = redh[64 + tid] + bB1;
                float hn = redh[128 + tid] + bB2;
                float rg = sigm(xr + hr);
                float zg = sigm(xz + hz);
                float ng = tanh_(xn + rg * hn);
                float hnew = (1.f - zg) * ng + zg * hprB;
                hprB = hnew;
                hbB[p2][tid] = pack1(hnew);
                yB[((size_t)b * S_LEN + tb) * UB + tid] = hnew;
                if (tid == 0) ast32(bprog + b, (u32)(tb + 1));
            }
        }
    }
}

// ---------------- dual FC + log_softmax ----------------
__global__ __launch_bounds__(256) void k_fc(const float* __restrict__ yB, const float* __restrict__ w1,
                                            const float* __restrict__ b1, const float* __restrict__ w2,
                                            const float* __restrict__ b2, const float* __restrict__ alpha,
                                            const float* __restrict__ beta, float* __restrict__ out) {
    __shared__ float yb[4][64];
    __shared__ float vb[4][256];
    int tid = threadIdx.x;
    size_t r0 = (size_t)blockIdx.x * 4;
    { int r = tid >> 6, k = tid & 63; yb[r][k] = yB[(r0 + r) * 64 + k]; }
    __syncthreads();
    int o = tid;
    float a1[4] = {0, 0, 0, 0}, a2[4] = {0, 0, 0, 0};
    for (int k = 0; k < 64; k += 4) {
        float4 u = *(const float4*)(w1 + o * 64 + k);
        float4 v = *(const float4*)(w2 + o * 64 + k);
#pragma unroll
        for (int r = 0; r < 4; r++) {
            float y0 = yb[r][k], y1 = yb[r][k + 1], y2 = yb[r][k + 2], y3 = yb[r][k + 3];
            a1[r] = fmaf(u.x, y0, fmaf(u.y, y1, fmaf(u.z, y2, fmaf(u.w, y3, a1[r]))));
            a2[r] = fmaf(v.x, y0, fmaf(v.y, y1, fmaf(v.z, y2, fmaf(v.w, y3, a2[r]))));
        }
    }
    float al = alpha[o], be = beta[o], c1 = b1[o], c2 = b2[o];
#pragma unroll
    for (int r = 0; r < 4; r++)
        vb[r][o] = al * tanh_(a1[r] + c1) + be * tanh_(a2[r] + c2);
    __syncthreads();
    int wv = tid >> 6, l = tid & 63;
    float x0 = vb[wv][l], x1 = vb[wv][64 + l], x2 = vb[wv][128 + l], x3 = vb[wv][192 + l];
    float m = fmaxf(fmaxf(x0, x1), fmaxf(x2, x3));
#pragma unroll
    for (int off = 1; off < 64; off <<= 1) m = fmaxf(m, __shfl_xor(m, off));
    float sum = __expf(x0 - m) + __expf(x1 - m) + __expf(x2 - m) + __expf(x3 - m);
#pragma unroll
    for (int off = 1; off < 64; off <<= 1) sum += __shfl_xor(sum, off);
    float lse = m + __logf(sum);
    float* po = out + (r0 + wv) * 256;
    po[l] = x0 - lse;
    po[64 + l] = x1 - lse;
    po[128 + l] = x2 - lse;
    po[192 + l] = x3 - lse;
}

extern "C" void kernel_launch(void* const* d_in, const int* in_sizes, int n_in,
                              void* d_out, int out_size, void* d_ws, size_t ws_size,
                              hipStream_t stream) {
    const float* features = (const float*)d_in[0];
    const int* periods = (const int*)d_in[1];
    const int* signals = (const int*)d_in[2];
    const float* gruA0 = (const float*)d_in[3];
    const float* gruB0 = (const float*)d_in[4];
    const float* period_emb = (const float*)d_in[5];
    const float* signal_emb = (const float*)d_in[6];
    const float* conv1_w = (const float*)d_in[7];
    const float* conv1_b = (const float*)d_in[8];
    const float* conv2_w = (const float*)d_in[9];
    const float* conv2_b = (const float*)d_in[10];
    const float* fd1_w = (const float*)d_in[11];
    const float* fd1_b = (const float*)d_in[12];
    const float* fd2_w = (const float*)d_in[13];
    const float* fd2_b = (const float*)d_in[14];
    const float* grua_wih = (const float*)d_in[15];
    const float* grua_whh = (const float*)d_in[16];
    const float* grua_bih = (const float*)d_in[17];
    const float* grua_bhh = (const float*)d_in[18];
    const float* grub_wih = (const float*)d_in[19];
    const float* grub_whh = (const float*)d_in[20];
    const float* grub_bih = (const float*)d_in[21];
    const float* grub_bhh = (const float*)d_in[22];
    const float* fc1_w = (const float*)d_in[23];
    const float* fc1_b = (const float*)d_in[24];
    const float* fc2_w = (const float*)d_in[25];
    const float* fc2_b = (const float*)d_in[26];
    const float* alpha = (const float*)d_in[27];
    const float* beta = (const float*)d_in[28];
    float* out = (float*)d_out;

    char* ws = (char*)d_ws;
    size_t off = 0;
    auto alloc = [&](size_t bytes) { void* p = ws + off; off += (bytes + 255) & ~(size_t)255; return p; };
    u16* xp = (u16*)alloc((size_t)16 * 5120 * 1152 * 2);
    u16* wihA = (u16*)alloc((size_t)1152 * 512 * 2);
    float* c1 = (float*)alloc((size_t)16 * 34 * 128 * 4);
    float* c2 = (float*)alloc((size_t)16 * 32 * 128 * 4);
    float* cc = (float*)alloc((size_t)16 * 32 * 128 * 4);
    float* cpart = (float*)alloc((size_t)16 * 32 * 192 * 4);
    float* yB = (float*)alloc((size_t)16 * 5120 * 64 * 4);
    u32* hEx = (u32*)alloc((size_t)49408 * 4);  // ring 16*8*3*128 + bprog(16) + pad
    u32* bprog = hEx + 49152;

    k_cvt<<<dim3(2304), dim3(256), 0, stream>>>(grua_wih, wihA);
    k_frame1<<<dim3(34, 16), dim3(128), 0, stream>>>(features, periods, period_emb, conv1_w, conv1_b, c1);
    k_frame2<<<dim3(32, 16), dim3(128), 0, stream>>>(c1, conv2_w, conv2_b, c2);
    k_fd<<<dim3(32, 16), dim3(128), 0, stream>>>(c2, fd1_w, fd1_b, fd2_w, fd2_b, cc);
    k_cpart<<<dim3(32, 16), dim3(192), 0, stream>>>(cc, grub_wih, grub_bih, cpart);
    k_init<<<dim3(193), dim3(256), 0, stream>>>(hEx);
    k_gemm<<<dim3(1280, 18), dim3(256), 0, stream>>>(signals, signal_emb, cc, wihA, grua_bih, xp);
    k_serial<<<dim3(64), dim3(512), 0, stream>>>(grua_whh, grua_bhh, grub_wih, grub_whh, grub_bhh,
                                                 xp, cpart, gruA0, gruB0, hEx, bprog, yB);
    k_fc<<<dim3(20480), dim3(256), 0, stream>>>(yB, fc1_w, fc1_b, fc2_w, fc2_b, alpha, beta, out);
}